// Round 1
// baseline (1321.681 us; speedup 1.0000x reference)
//
#include <hip/hip_runtime.h>
#include <hip/hip_bf16.h>
#include <cstdint>
#include <cstddef>

// ---------------------------------------------------------------------------
// GAT x3 + MLP head, all fp32.
// Per layer: hs = X @ W  (one GEMM); alpha_s = X@(W a_s); alpha_d = X@(Wd a_d);
// per-edge logits from alpha gather; CSR-by-dst online-softmax aggregation.
// ---------------------------------------------------------------------------

// ---------------- CSR build ----------------
__global__ void count_deg_kernel(const int* __restrict__ dst, int* __restrict__ deg, int E) {
  int i = blockIdx.x * blockDim.x + threadIdx.x;
  if (i < E) atomicAdd(&deg[dst[i]], 1);
}

__global__ __launch_bounds__(1024) void exscan_kernel(const int* __restrict__ deg,
                                                      int* __restrict__ row_ptr, int n) {
  __shared__ int sdata[1024];
  __shared__ int s_run;
  int t = threadIdx.x;
  if (t == 0) s_run = 0;
  __syncthreads();
  for (int base = 0; base < n; base += 1024) {
    int i = base + t;
    int x = (i < n) ? deg[i] : 0;
    sdata[t] = x;
    __syncthreads();
    #pragma unroll
    for (int off = 1; off < 1024; off <<= 1) {
      int v = (t >= off) ? sdata[t - off] : 0;
      __syncthreads();
      sdata[t] += v;
      __syncthreads();
    }
    int incl = sdata[t];
    int run = s_run;
    if (i < n) row_ptr[i] = run + incl - x;  // exclusive
    __syncthreads();
    if (t == 1023) s_run = run + incl;
    __syncthreads();
  }
  if (t == 0) row_ptr[n] = s_run;
}

__global__ void copy_int_kernel(const int* __restrict__ src, int* __restrict__ dst, int n) {
  int i = blockIdx.x * blockDim.x + threadIdx.x;
  if (i < n) dst[i] = src[i];
}

__global__ void fill_csr_kernel(const int* __restrict__ src, const int* __restrict__ dst,
                                int* __restrict__ cursor, int* __restrict__ src_sorted, int E) {
  int i = blockIdx.x * blockDim.x + threadIdx.x;
  if (i < E) {
    int d = dst[i];
    int pos = atomicAdd(&cursor[d], 1);
    src_sorted[pos] = src[i];
  }
}

// ---------------- tiny: v = W @ a  (v[d] = sum_h W[d*H+h]*a[h]) ----------------
__global__ void make_v_kernel(const float* __restrict__ W, const float* __restrict__ a,
                              float* __restrict__ v, int D, int H) {
  int d = blockIdx.x * blockDim.x + threadIdx.x;
  if (d < D) {
    float s = 0.f;
    for (int h = 0; h < H; ++h) s = fmaf(W[d * H + h], a[h], s);
    v[d] = s;
  }
}

// ---------------- alpha_s / alpha_d: per-node dot(X_row, v) ----------------
__global__ void alpha_kernel(const float* __restrict__ X, const float* __restrict__ vs,
                             const float* __restrict__ vd, float* __restrict__ as_,
                             float* __restrict__ ad_, int n) {
  int wid = blockIdx.x * (blockDim.x >> 6) + (threadIdx.x >> 6);
  int lane = threadIdx.x & 63;
  if (wid >= n) return;
  float2 xv = ((const float2*)X)[(size_t)wid * 64 + lane];
  float2 v1 = ((const float2*)vs)[lane];
  float2 v2 = ((const float2*)vd)[lane];
  float ps = xv.x * v1.x + xv.y * v1.y;
  float pd = xv.x * v2.x + xv.y * v2.y;
  #pragma unroll
  for (int off = 32; off > 0; off >>= 1) {
    ps += __shfl_down(ps, off, 64);
    pd += __shfl_down(pd, off, 64);
  }
  if (lane == 0) { as_[wid] = ps; ad_[wid] = pd; }
}

// ---------------- GAT aggregation: one wave per dst node ----------------
__global__ void gat_aggregate_kernel(const float* __restrict__ hs,
                                     const float* __restrict__ alpha_s,
                                     const float* __restrict__ alpha_d,
                                     const int* __restrict__ row_ptr,
                                     const int* __restrict__ src_sorted,
                                     const float* __restrict__ bias,
                                     float* __restrict__ out, int n) {
  int wid = blockIdx.x * (blockDim.x >> 6) + (threadIdx.x >> 6);
  int lane = threadIdx.x & 63;
  if (wid >= n) return;
  int beg = row_ptr[wid], end = row_ptr[wid + 1];
  float ad = alpha_d[wid];
  float m = -INFINITY, s = 0.f, a0 = 0.f, a1 = 0.f;
  const float2* hs2 = (const float2*)hs;
  for (int j = beg; j < end; ++j) {
    int u = src_sorted[j];
    float e = alpha_s[u] + ad;
    e = (e > 0.f) ? e : 0.2f * e;              // leaky_relu 0.2
    float mn = fmaxf(m, e);
    float scale = __expf(m - mn);              // exp(-inf)=0 on first edge
    float p = __expf(e - mn);
    float2 h = hs2[(size_t)u * 64 + lane];
    s = s * scale + p;
    a0 = fmaf(p, h.x, a0 * scale);
    a1 = fmaf(p, h.y, a1 * scale);
    m = mn;
  }
  float inv = 1.f / (s + 1e-16f);
  float2 b = ((const float2*)bias)[lane];
  float o0 = fmaxf(fmaf(a0, inv, b.x), 0.f);   // + bias, relu
  float o1 = fmaxf(fmaf(a1, inv, b.y), 0.f);
  ((float2*)out)[(size_t)wid * 64 + lane] = make_float2(o0, o1);
}

// ---------------- fp32 GEMM, K=128 resident: C[N,M] = A[N,128] @ W[128,M] ----------------
template <int M, bool RELU, bool HASBIAS>
__global__ __launch_bounds__(512, 1) void gemm_k128_kernel(const float* __restrict__ A,
                                                           const float* __restrict__ W,
                                                           const float* __restrict__ bias,
                                                           float* __restrict__ C, int n) {
  __shared__ float sA[128 * 128];
  __shared__ float sW[128 * M];
  const int t = threadIdx.x;
  const int row0 = blockIdx.x * 128;

  for (int i = t; i < (128 * M) / 4; i += 512)
    ((float4*)sW)[i] = ((const float4*)W)[i];
  for (int i = t; i < (128 * 128) / 4; i += 512) {
    int r = i >> 5, c = i & 31;
    int gr = row0 + r;
    float4 v = make_float4(0.f, 0.f, 0.f, 0.f);
    if (gr < n) v = ((const float4*)(A + (size_t)gr * 128))[c];
    ((float4*)(sA + r * 128))[c] = v;
  }
  __syncthreads();

  const int tx = t & 31;
  const int ty = t >> 5;         // 0..15 -> rows ty*8..ty*8+7
  constexpr int CPT = M / 32;    // 4 (M=128) or 2 (M=64)

  float acc[8][CPT];
  #pragma unroll
  for (int i = 0; i < 8; ++i)
    #pragma unroll
    for (int j = 0; j < CPT; ++j) acc[i][j] = 0.f;

  #pragma unroll 4
  for (int k = 0; k < 128; k += 4) {
    float a[8][4];
    #pragma unroll
    for (int i = 0; i < 8; ++i) {
      float4 av = *(const float4*)(sA + (ty * 8 + i) * 128 + k);
      a[i][0] = av.x; a[i][1] = av.y; a[i][2] = av.z; a[i][3] = av.w;
    }
    #pragma unroll
    for (int kk = 0; kk < 4; ++kk) {
      float w[CPT];
      if (CPT == 4) {
        float4 wv = *(const float4*)(sW + (k + kk) * M + tx * 4);
        w[0] = wv.x; w[1] = wv.y; w[2] = wv.z; w[3] = wv.w;
      } else {
        float2 wv = *(const float2*)(sW + (k + kk) * M + tx * 2);
        w[0] = wv.x; w[1] = wv.y;
      }
      #pragma unroll
      for (int i = 0; i < 8; ++i)
        #pragma unroll
        for (int j = 0; j < CPT; ++j) acc[i][j] = fmaf(a[i][kk], w[j], acc[i][j]);
    }
  }

  #pragma unroll
  for (int i = 0; i < 8; ++i) {
    int gr = row0 + ty * 8 + i;
    if (gr < n) {
      #pragma unroll
      for (int j = 0; j < CPT; ++j) {
        float v = acc[i][j];
        if (HASBIAS) v += bias[tx * CPT + j];
        if (RELU) v = fmaxf(v, 0.f);
        C[(size_t)gr * M + tx * CPT + j] = v;
      }
    }
  }
}

// ---------------------------------------------------------------------------
extern "C" void kernel_launch(void* const* d_in, const int* in_sizes, int n_in,
                              void* d_out, int out_size, void* d_ws, size_t ws_size,
                              hipStream_t stream) {
  const float* x     = (const float*)d_in[0];
  const int*   eidx  = (const int*)d_in[1];
  const float* W1s   = (const float*)d_in[2];
  const float* W1d   = (const float*)d_in[3];
  const float* a1s   = (const float*)d_in[4];
  const float* a1d   = (const float*)d_in[5];
  const float* b1    = (const float*)d_in[6];
  const float* W2    = (const float*)d_in[7];
  const float* a2s   = (const float*)d_in[8];
  const float* a2d   = (const float*)d_in[9];
  const float* b2    = (const float*)d_in[10];
  const float* W3    = (const float*)d_in[11];
  const float* a3s   = (const float*)d_in[12];
  const float* a3d   = (const float*)d_in[13];
  const float* b3    = (const float*)d_in[14];
  const float* Wl1   = (const float*)d_in[15];
  const float* bl1   = (const float*)d_in[16];
  const float* Wl2   = (const float*)d_in[17];
  const float* bl2   = (const float*)d_in[18];
  float* out = (float*)d_out;

  const int N = in_sizes[0] / 128;
  const int E = in_sizes[1] / 2;
  const int* src = eidx;
  const int* dst = eidx + E;

  // ---- workspace layout (512B aligned bump allocator) ----
  char* base = (char*)d_ws;
  size_t off = 0;
  auto alloc = [&](size_t bytes) -> void* {
    void* p = base + off;
    off += (bytes + 511) & ~(size_t)511;
    return p;
  };
  float* P       = (float*)alloc((size_t)N * 128 * 4);  // ping
  float* Q       = (float*)alloc((size_t)N * 128 * 4);  // pong
  float* alpha_s = (float*)alloc((size_t)N * 4);
  float* alpha_d = (float*)alloc((size_t)N * 4);
  float* vs      = (float*)alloc(128 * 4);
  float* vd      = (float*)alloc(128 * 4);
  int* row_ptr   = (int*)alloc((size_t)(N + 1) * 4);
  int* cursor    = (int*)alloc((size_t)N * 4);
  int* src_sorted= (int*)alloc((size_t)E * 4);
  (void)ws_size;

  const int TB = 256;
  const int nwaveblk = (N + 3) / 4;          // 4 waves/block, 1 node/wave
  const int egrid = (E + TB - 1) / TB;
  const int ggrid = (N + 127) / 128;

  // ---- CSR build (reused by all 3 layers) ----
  hipMemsetAsync(cursor, 0, (size_t)N * 4, stream);
  count_deg_kernel<<<egrid, TB, 0, stream>>>(dst, cursor, E);
  exscan_kernel<<<1, 1024, 0, stream>>>(cursor, row_ptr, N);
  copy_int_kernel<<<(N + TB - 1) / TB, TB, 0, stream>>>(row_ptr, cursor, N);
  fill_csr_kernel<<<egrid, TB, 0, stream>>>(src, dst, cursor, src_sorted, E);

  // ---- layer 1: x -> P ----
  make_v_kernel<<<1, 128, 0, stream>>>(W1s, a1s, vs, 128, 128);
  make_v_kernel<<<1, 128, 0, stream>>>(W1d, a1d, vd, 128, 128);
  alpha_kernel<<<nwaveblk, TB, 0, stream>>>(x, vs, vd, alpha_s, alpha_d, N);
  gemm_k128_kernel<128, false, false><<<ggrid, 512, 0, stream>>>(x, W1s, nullptr, Q, N);
  gat_aggregate_kernel<<<nwaveblk, TB, 0, stream>>>(Q, alpha_s, alpha_d, row_ptr, src_sorted,
                                                    b1, P, N);

  // ---- layer 2: P -> P (via Q) ----
  make_v_kernel<<<1, 128, 0, stream>>>(W2, a2s, vs, 128, 128);
  make_v_kernel<<<1, 128, 0, stream>>>(W2, a2d, vd, 128, 128);
  alpha_kernel<<<nwaveblk, TB, 0, stream>>>(P, vs, vd, alpha_s, alpha_d, N);
  gemm_k128_kernel<128, false, false><<<ggrid, 512, 0, stream>>>(P, W2, nullptr, Q, N);
  gat_aggregate_kernel<<<nwaveblk, TB, 0, stream>>>(Q, alpha_s, alpha_d, row_ptr, src_sorted,
                                                    b2, P, N);

  // ---- layer 3: P -> P (via Q) ----
  make_v_kernel<<<1, 128, 0, stream>>>(W3, a3s, vs, 128, 128);
  make_v_kernel<<<1, 128, 0, stream>>>(W3, a3d, vd, 128, 128);
  alpha_kernel<<<nwaveblk, TB, 0, stream>>>(P, vs, vd, alpha_s, alpha_d, N);
  gemm_k128_kernel<128, false, false><<<ggrid, 512, 0, stream>>>(P, W3, nullptr, Q, N);
  gat_aggregate_kernel<<<nwaveblk, TB, 0, stream>>>(Q, alpha_s, alpha_d, row_ptr, src_sorted,
                                                    b3, P, N);

  // ---- MLP head ----
  gemm_k128_kernel<128, true, true><<<ggrid, 512, 0, stream>>>(P, Wl1, bl1, Q, N);
  gemm_k128_kernel<64, false, true><<<ggrid, 512, 0, stream>>>(Q, Wl2, bl2, out, N);
}

// Round 2
// 933.794 us; speedup vs baseline: 1.4154x; 1.4154x over previous
//
#include <hip/hip_runtime.h>
#include <hip/hip_bf16.h>
#include <cstdint>
#include <cstddef>

// ---------------------------------------------------------------------------
// GAT x3 + MLP head, all fp32.
// Per layer: hs = X @ W (one GEMM); alpha_s/d per node; per-edge p=exp(lrelu(.))
// precomputed (no online max needed -- logits bounded); CSR-by-dst aggregation
// with 4 independent accumulator chains (4 gathers in flight per wave).
// ---------------------------------------------------------------------------

// ---------------- CSR build ----------------
__global__ void count_deg_kernel(const int* __restrict__ dst, int* __restrict__ deg, int E) {
  int i = blockIdx.x * blockDim.x + threadIdx.x;
  if (i < E) atomicAdd(&deg[dst[i]], 1);
}

__global__ __launch_bounds__(1024) void block_sum_kernel(const int* __restrict__ deg,
                                                         int* __restrict__ bsum, int n) {
  int t = threadIdx.x, i = blockIdx.x * 1024 + t;
  int x = (i < n) ? deg[i] : 0;
  #pragma unroll
  for (int off = 32; off >= 1; off >>= 1) x += __shfl_down(x, off, 64);
  __shared__ int ws[16];
  if ((t & 63) == 0) ws[t >> 6] = x;
  __syncthreads();
  if (t == 0) {
    int s = 0;
    #pragma unroll
    for (int w = 0; w < 16; ++w) s += ws[w];
    bsum[blockIdx.x] = s;
  }
}

// nb <= 128 required (N <= 131072)
__global__ __launch_bounds__(128) void scan_bsum_kernel(const int* __restrict__ bsum,
                                                        int* __restrict__ boff, int nb,
                                                        int* __restrict__ row_ptr, int n) {
  __shared__ int s[128];
  int t = threadIdx.x;
  int x = (t < nb) ? bsum[t] : 0;
  s[t] = x;
  __syncthreads();
  #pragma unroll
  for (int off = 1; off < 128; off <<= 1) {
    int v = (t >= off) ? s[t - off] : 0;
    __syncthreads();
    s[t] += v;
    __syncthreads();
  }
  if (t < nb) boff[t] = s[t] - x;
  if (t == 127) row_ptr[n] = s[127];
}

__global__ __launch_bounds__(1024) void block_exscan_kernel(const int* __restrict__ deg,
                                                            const int* __restrict__ boff,
                                                            int* __restrict__ row_ptr,
                                                            int* __restrict__ cursor, int n) {
  int t = threadIdx.x, i = blockIdx.x * 1024 + t;
  int lane = t & 63, wid = t >> 6;
  int x = (i < n) ? deg[i] : 0;
  int v = x;
  #pragma unroll
  for (int off = 1; off < 64; off <<= 1) {
    int tt = __shfl_up(v, off, 64);
    if (lane >= off) v += tt;
  }
  __shared__ int ws[16];
  if (lane == 63) ws[wid] = v;
  __syncthreads();
  if (t == 0) {
    int run = 0;
    #pragma unroll
    for (int w = 0; w < 16; ++w) { int tmp = ws[w]; ws[w] = run; run += tmp; }
  }
  __syncthreads();
  int excl = (v - x) + ws[wid] + boff[blockIdx.x];
  if (i < n) { row_ptr[i] = excl; cursor[i] = excl; }
}

__global__ void fill_csr_kernel(const int* __restrict__ src, const int* __restrict__ dst,
                                int* __restrict__ cursor, int* __restrict__ src_sorted,
                                int* __restrict__ dst_sorted, int E) {
  int i = blockIdx.x * blockDim.x + threadIdx.x;
  if (i < E) {
    int d = dst[i];
    int pos = atomicAdd(&cursor[d], 1);
    src_sorted[pos] = src[i];
    dst_sorted[pos] = d;
  }
}

// ---------------- vs = Wsrc @ a_s, vd = Wdst @ a_d (one wave per output) ----------------
__global__ void make_v2_kernel(const float* __restrict__ Ws, const float* __restrict__ as_,
                               const float* __restrict__ Wd, const float* __restrict__ ad_,
                               float* __restrict__ vs, float* __restrict__ vd) {
  int gw = blockIdx.x * (blockDim.x >> 6) + (threadIdx.x >> 6);  // 0..255
  int lane = threadIdx.x & 63;
  int d = gw & 127;
  const float* W = (gw < 128) ? Ws : Wd;
  const float* a = (gw < 128) ? as_ : ad_;
  float2 w0 = ((const float2*)(W + d * 128))[lane];
  float2 a0 = ((const float2*)a)[lane];
  float p = w0.x * a0.x + w0.y * a0.y;
  #pragma unroll
  for (int off = 32; off >= 1; off >>= 1) p += __shfl_down(p, off, 64);
  if (lane == 0) ((gw < 128) ? vs : vd)[d] = p;
}

// ---------------- alpha_s / alpha_d: per-node dot(X_row, v) ----------------
__global__ void alpha_kernel(const float* __restrict__ X, const float* __restrict__ vs,
                             const float* __restrict__ vd, float* __restrict__ as_,
                             float* __restrict__ ad_, int n) {
  int wid = blockIdx.x * (blockDim.x >> 6) + (threadIdx.x >> 6);
  int lane = threadIdx.x & 63;
  if (wid >= n) return;
  float2 xv = ((const float2*)X)[(size_t)wid * 64 + lane];
  float2 v1 = ((const float2*)vs)[lane];
  float2 v2 = ((const float2*)vd)[lane];
  float ps = xv.x * v1.x + xv.y * v1.y;
  float pd = xv.x * v2.x + xv.y * v2.y;
  #pragma unroll
  for (int off = 32; off > 0; off >>= 1) {
    ps += __shfl_down(ps, off, 64);
    pd += __shfl_down(pd, off, 64);
  }
  if (lane == 0) { as_[wid] = ps; ad_[wid] = pd; }
}

// ---------------- per-edge attention numerator p = exp(leaky_relu(as+ad)) ----------------
// No max-subtraction needed: logits are bounded (|e| << 80), fp32 exp is exact
// enough and softmax is shift-invariant, so result matches ref within rounding.
__global__ void elogit_kernel(const int* __restrict__ src_sorted,
                              const int* __restrict__ dst_sorted,
                              const float* __restrict__ as_, const float* __restrict__ ad_,
                              float* __restrict__ p_sorted, int E) {
  int j = blockIdx.x * blockDim.x + threadIdx.x;
  if (j < E) {
    float e = as_[src_sorted[j]] + ad_[dst_sorted[j]];
    e = (e > 0.f) ? e : 0.2f * e;
    p_sorted[j] = __expf(e);
  }
}

// ---------------- GAT aggregation: one wave per dst node, 4 chains ----------------
__global__ void gat_aggregate_kernel(const float* __restrict__ hs,
                                     const float* __restrict__ p_sorted,
                                     const int* __restrict__ row_ptr,
                                     const int* __restrict__ src_sorted,
                                     const float* __restrict__ bias,
                                     float* __restrict__ out, int n) {
  int wid = blockIdx.x * (blockDim.x >> 6) + (threadIdx.x >> 6);
  int lane = threadIdx.x & 63;
  if (wid >= n) return;
  int beg = row_ptr[wid], end = row_ptr[wid + 1];
  const float2* hs2 = (const float2*)hs;
  float s0 = 0.f, s1 = 0.f, s2 = 0.f, s3 = 0.f;
  float a0x = 0.f, a0y = 0.f, a1x = 0.f, a1y = 0.f;
  float a2x = 0.f, a2y = 0.f, a3x = 0.f, a3y = 0.f;
  int j = beg;
  for (; j + 4 <= end; j += 4) {
    int u0 = src_sorted[j + 0], u1 = src_sorted[j + 1];
    int u2 = src_sorted[j + 2], u3 = src_sorted[j + 3];
    float p0 = p_sorted[j + 0], p1 = p_sorted[j + 1];
    float p2 = p_sorted[j + 2], p3 = p_sorted[j + 3];
    float2 h0 = hs2[(size_t)u0 * 64 + lane];
    float2 h1 = hs2[(size_t)u1 * 64 + lane];
    float2 h2 = hs2[(size_t)u2 * 64 + lane];
    float2 h3 = hs2[(size_t)u3 * 64 + lane];
    s0 += p0; a0x = fmaf(p0, h0.x, a0x); a0y = fmaf(p0, h0.y, a0y);
    s1 += p1; a1x = fmaf(p1, h1.x, a1x); a1y = fmaf(p1, h1.y, a1y);
    s2 += p2; a2x = fmaf(p2, h2.x, a2x); a2y = fmaf(p2, h2.y, a2y);
    s3 += p3; a3x = fmaf(p3, h3.x, a3x); a3y = fmaf(p3, h3.y, a3y);
  }
  for (; j < end; ++j) {
    int u0 = src_sorted[j];
    float p0 = p_sorted[j];
    float2 h0 = hs2[(size_t)u0 * 64 + lane];
    s0 += p0; a0x = fmaf(p0, h0.x, a0x); a0y = fmaf(p0, h0.y, a0y);
  }
  float s = (s0 + s1) + (s2 + s3);
  float ax = (a0x + a1x) + (a2x + a3x);
  float ay = (a0y + a1y) + (a2y + a3y);
  float inv = 1.f / (s + 1e-16f);
  float2 b = ((const float2*)bias)[lane];
  float o0 = fmaxf(fmaf(ax, inv, b.x), 0.f);
  float o1 = fmaxf(fmaf(ay, inv, b.y), 0.f);
  ((float2*)out)[(size_t)wid * 64 + lane] = make_float2(o0, o1);
}

// ---------------- fp32 GEMM, K=128 resident: C[N,M] = A[N,128] @ W[128,M] ----------------
template <int M, bool RELU, bool HASBIAS>
__global__ __launch_bounds__(512, 1) void gemm_k128_kernel(const float* __restrict__ A,
                                                           const float* __restrict__ W,
                                                           const float* __restrict__ bias,
                                                           float* __restrict__ C, int n) {
  __shared__ float sA[128 * 128];
  __shared__ float sW[128 * M];
  const int t = threadIdx.x;
  const int row0 = blockIdx.x * 128;

  for (int i = t; i < (128 * M) / 4; i += 512)
    ((float4*)sW)[i] = ((const float4*)W)[i];
  for (int i = t; i < (128 * 128) / 4; i += 512) {
    int r = i >> 5, c = i & 31;
    int gr = row0 + r;
    float4 v = make_float4(0.f, 0.f, 0.f, 0.f);
    if (gr < n) v = ((const float4*)(A + (size_t)gr * 128))[c];
    ((float4*)(sA + r * 128))[c] = v;
  }
  __syncthreads();

  const int tx = t & 31;
  const int ty = t >> 5;         // 0..15 -> rows ty*8..ty*8+7
  constexpr int CPT = M / 32;    // 4 (M=128) or 2 (M=64)

  float acc[8][CPT];
  #pragma unroll
  for (int i = 0; i < 8; ++i)
    #pragma unroll
    for (int j = 0; j < CPT; ++j) acc[i][j] = 0.f;

  #pragma unroll 4
  for (int k = 0; k < 128; k += 4) {
    float a[8][4];
    #pragma unroll
    for (int i = 0; i < 8; ++i) {
      float4 av = *(const float4*)(sA + (ty * 8 + i) * 128 + k);
      a[i][0] = av.x; a[i][1] = av.y; a[i][2] = av.z; a[i][3] = av.w;
    }
    #pragma unroll
    for (int kk = 0; kk < 4; ++kk) {
      float w[CPT];
      if (CPT == 4) {
        float4 wv = *(const float4*)(sW + (k + kk) * M + tx * 4);
        w[0] = wv.x; w[1] = wv.y; w[2] = wv.z; w[3] = wv.w;
      } else {
        float2 wv = *(const float2*)(sW + (k + kk) * M + tx * 2);
        w[0] = wv.x; w[1] = wv.y;
      }
      #pragma unroll
      for (int i = 0; i < 8; ++i)
        #pragma unroll
        for (int j = 0; j < CPT; ++j) acc[i][j] = fmaf(a[i][kk], w[j], acc[i][j]);
    }
  }

  #pragma unroll
  for (int i = 0; i < 8; ++i) {
    int gr = row0 + ty * 8 + i;
    if (gr < n) {
      #pragma unroll
      for (int j = 0; j < CPT; ++j) {
        float v = acc[i][j];
        if (HASBIAS) v += bias[tx * CPT + j];
        if (RELU) v = fmaxf(v, 0.f);
        C[(size_t)gr * M + tx * CPT + j] = v;
      }
    }
  }
}

// ---------------------------------------------------------------------------
extern "C" void kernel_launch(void* const* d_in, const int* in_sizes, int n_in,
                              void* d_out, int out_size, void* d_ws, size_t ws_size,
                              hipStream_t stream) {
  const float* x     = (const float*)d_in[0];
  const int*   eidx  = (const int*)d_in[1];
  const float* W1s   = (const float*)d_in[2];
  const float* W1d   = (const float*)d_in[3];
  const float* a1s   = (const float*)d_in[4];
  const float* a1d   = (const float*)d_in[5];
  const float* b1    = (const float*)d_in[6];
  const float* W2    = (const float*)d_in[7];
  const float* a2s   = (const float*)d_in[8];
  const float* a2d   = (const float*)d_in[9];
  const float* b2    = (const float*)d_in[10];
  const float* W3    = (const float*)d_in[11];
  const float* a3s   = (const float*)d_in[12];
  const float* a3d   = (const float*)d_in[13];
  const float* b3    = (const float*)d_in[14];
  const float* Wl1   = (const float*)d_in[15];
  const float* bl1   = (const float*)d_in[16];
  const float* Wl2   = (const float*)d_in[17];
  const float* bl2   = (const float*)d_in[18];
  float* out = (float*)d_out;

  const int N = in_sizes[0] / 128;
  const int E = in_sizes[1] / 2;
  const int* src = eidx;
  const int* dst = eidx + E;

  // ---- workspace layout (512B aligned bump allocator) ----
  char* base = (char*)d_ws;
  size_t off = 0;
  auto alloc = [&](size_t bytes) -> void* {
    void* p = base + off;
    off += (bytes + 511) & ~(size_t)511;
    return p;
  };
  float* P        = (float*)alloc((size_t)N * 128 * 4);  // ping
  float* Q        = (float*)alloc((size_t)N * 128 * 4);  // pong
  float* alpha_s  = (float*)alloc((size_t)N * 4);
  float* alpha_d  = (float*)alloc((size_t)N * 4);
  float* vs       = (float*)alloc(128 * 4);
  float* vd       = (float*)alloc(128 * 4);
  int* deg        = (int*)alloc((size_t)N * 4);
  int* row_ptr    = (int*)alloc((size_t)(N + 1) * 4);
  int* cursor     = (int*)alloc((size_t)N * 4);
  int* bsum       = (int*)alloc(128 * 4);
  int* boff       = (int*)alloc(128 * 4);
  int* src_sorted = (int*)alloc((size_t)E * 4);
  int* dst_sorted = (int*)alloc((size_t)E * 4);
  float* p_sorted = (float*)alloc((size_t)E * 4);
  (void)ws_size;

  const int TB = 256;
  const int nwaveblk = (N + 3) / 4;          // 4 waves/block, 1 node/wave
  const int egrid = (E + TB - 1) / TB;
  const int ggrid = (N + 127) / 128;
  const int nb = (N + 1023) / 1024;          // <= 128

  // ---- CSR build (reused by all 3 layers) ----
  hipMemsetAsync(deg, 0, (size_t)N * 4, stream);
  count_deg_kernel<<<egrid, TB, 0, stream>>>(dst, deg, E);
  block_sum_kernel<<<nb, 1024, 0, stream>>>(deg, bsum, N);
  scan_bsum_kernel<<<1, 128, 0, stream>>>(bsum, boff, nb, row_ptr, N);
  block_exscan_kernel<<<nb, 1024, 0, stream>>>(deg, boff, row_ptr, cursor, N);
  fill_csr_kernel<<<egrid, TB, 0, stream>>>(src, dst, cursor, src_sorted, dst_sorted, E);

  // ---- layer 1: x -> P ----
  make_v2_kernel<<<64, 256, 0, stream>>>(W1s, a1s, W1d, a1d, vs, vd);
  alpha_kernel<<<nwaveblk, TB, 0, stream>>>(x, vs, vd, alpha_s, alpha_d, N);
  elogit_kernel<<<egrid, TB, 0, stream>>>(src_sorted, dst_sorted, alpha_s, alpha_d, p_sorted, E);
  gemm_k128_kernel<128, false, false><<<ggrid, 512, 0, stream>>>(x, W1s, nullptr, Q, N);
  gat_aggregate_kernel<<<nwaveblk, TB, 0, stream>>>(Q, p_sorted, row_ptr, src_sorted, b1, P, N);

  // ---- layer 2: P -> P (via Q) ----
  make_v2_kernel<<<64, 256, 0, stream>>>(W2, a2s, W2, a2d, vs, vd);
  alpha_kernel<<<nwaveblk, TB, 0, stream>>>(P, vs, vd, alpha_s, alpha_d, N);
  elogit_kernel<<<egrid, TB, 0, stream>>>(src_sorted, dst_sorted, alpha_s, alpha_d, p_sorted, E);
  gemm_k128_kernel<128, false, false><<<ggrid, 512, 0, stream>>>(P, W2, nullptr, Q, N);
  gat_aggregate_kernel<<<nwaveblk, TB, 0, stream>>>(Q, p_sorted, row_ptr, src_sorted, b2, P, N);

  // ---- layer 3: P -> P (via Q) ----
  make_v2_kernel<<<64, 256, 0, stream>>>(W3, a3s, W3, a3d, vs, vd);
  alpha_kernel<<<nwaveblk, TB, 0, stream>>>(P, vs, vd, alpha_s, alpha_d, N);
  elogit_kernel<<<egrid, TB, 0, stream>>>(src_sorted, dst_sorted, alpha_s, alpha_d, p_sorted, E);
  gemm_k128_kernel<128, false, false><<<ggrid, 512, 0, stream>>>(P, W3, nullptr, Q, N);
  gat_aggregate_kernel<<<nwaveblk, TB, 0, stream>>>(Q, p_sorted, row_ptr, src_sorted, b3, P, N);

  // ---- MLP head ----
  gemm_k128_kernel<128, true, true><<<ggrid, 512, 0, stream>>>(P, Wl1, bl1, Q, N);
  gemm_k128_kernel<64, false, true><<<ggrid, 512, 0, stream>>>(Q, Wl2, bl2, out, N);
}

// Round 3
// 795.335 us; speedup vs baseline: 1.6618x; 1.1741x over previous
//
#include <hip/hip_runtime.h>
#include <hip/hip_bf16.h>
#include <cstdint>
#include <cstddef>

// ---------------------------------------------------------------------------
// GAT x3 + MLP head. fp32 compute; messages (GEMM output Q) stored bf16.
// Per layer: hs = X @ W (one GEMM, bf16 out); alpha_s/d per node (fp32);
// CSR-by-dst aggregation with inline p = exp(lrelu(alpha_s[src]+alpha_d[dst]))
// and 4 independent accumulator chains.
// ---------------------------------------------------------------------------

__device__ __forceinline__ ushort f2bf_rne(float f) {
  uint u = __float_as_uint(f);
  u += 0x7FFFu + ((u >> 16) & 1u);
  return (ushort)(u >> 16);
}

// ---------------- CSR build ----------------
__global__ void count_deg_kernel(const int* __restrict__ dst, int* __restrict__ deg, int E) {
  int i = blockIdx.x * blockDim.x + threadIdx.x;
  if (i < E) atomicAdd(&deg[dst[i]], 1);
}

__global__ __launch_bounds__(1024) void block_sum_kernel(const int* __restrict__ deg,
                                                         int* __restrict__ bsum, int n) {
  int t = threadIdx.x, i = blockIdx.x * 1024 + t;
  int x = (i < n) ? deg[i] : 0;
  #pragma unroll
  for (int off = 32; off >= 1; off >>= 1) x += __shfl_down(x, off, 64);
  __shared__ int ws[16];
  if ((t & 63) == 0) ws[t >> 6] = x;
  __syncthreads();
  if (t == 0) {
    int s = 0;
    #pragma unroll
    for (int w = 0; w < 16; ++w) s += ws[w];
    bsum[blockIdx.x] = s;
  }
}

// nb <= 128 required (N <= 131072)
__global__ __launch_bounds__(128) void scan_bsum_kernel(const int* __restrict__ bsum,
                                                        int* __restrict__ boff, int nb,
                                                        int* __restrict__ row_ptr, int n) {
  __shared__ int s[128];
  int t = threadIdx.x;
  int x = (t < nb) ? bsum[t] : 0;
  s[t] = x;
  __syncthreads();
  #pragma unroll
  for (int off = 1; off < 128; off <<= 1) {
    int v = (t >= off) ? s[t - off] : 0;
    __syncthreads();
    s[t] += v;
    __syncthreads();
  }
  if (t < nb) boff[t] = s[t] - x;
  if (t == 127) row_ptr[n] = s[127];
}

__global__ __launch_bounds__(1024) void block_exscan_kernel(const int* __restrict__ deg,
                                                            const int* __restrict__ boff,
                                                            int* __restrict__ row_ptr,
                                                            int* __restrict__ cursor, int n) {
  int t = threadIdx.x, i = blockIdx.x * 1024 + t;
  int lane = t & 63, wid = t >> 6;
  int x = (i < n) ? deg[i] : 0;
  int v = x;
  #pragma unroll
  for (int off = 1; off < 64; off <<= 1) {
    int tt = __shfl_up(v, off, 64);
    if (lane >= off) v += tt;
  }
  __shared__ int ws[16];
  if (lane == 63) ws[wid] = v;
  __syncthreads();
  if (t == 0) {
    int run = 0;
    #pragma unroll
    for (int w = 0; w < 16; ++w) { int tmp = ws[w]; ws[w] = run; run += tmp; }
  }
  __syncthreads();
  int excl = (v - x) + ws[wid] + boff[blockIdx.x];
  if (i < n) { row_ptr[i] = excl; cursor[i] = excl; }
}

__global__ void fill_csr_kernel(const int* __restrict__ src, const int* __restrict__ dst,
                                int* __restrict__ cursor, int* __restrict__ src_sorted, int E) {
  int i = blockIdx.x * blockDim.x + threadIdx.x;
  if (i < E) {
    int d = dst[i];
    int pos = atomicAdd(&cursor[d], 1);
    src_sorted[pos] = src[i];
  }
}

// ---------------- vs = Wsrc @ a_s, vd = Wdst @ a_d (one wave per output) ----------------
__global__ void make_v2_kernel(const float* __restrict__ Ws, const float* __restrict__ as_,
                               const float* __restrict__ Wd, const float* __restrict__ ad_,
                               float* __restrict__ vs, float* __restrict__ vd) {
  int gw = blockIdx.x * (blockDim.x >> 6) + (threadIdx.x >> 6);  // 0..255
  int lane = threadIdx.x & 63;
  int d = gw & 127;
  const float* W = (gw < 128) ? Ws : Wd;
  const float* a = (gw < 128) ? as_ : ad_;
  float2 w0 = ((const float2*)(W + d * 128))[lane];
  float2 a0 = ((const float2*)a)[lane];
  float p = w0.x * a0.x + w0.y * a0.y;
  #pragma unroll
  for (int off = 32; off >= 1; off >>= 1) p += __shfl_down(p, off, 64);
  if (lane == 0) ((gw < 128) ? vs : vd)[d] = p;
}

// ---------------- alpha_s / alpha_d: per-node dot(X_row, v), X fp32 ----------------
__global__ void alpha_kernel(const float* __restrict__ X, const float* __restrict__ vs,
                             const float* __restrict__ vd, float* __restrict__ as_,
                             float* __restrict__ ad_, int n) {
  int wid = blockIdx.x * (blockDim.x >> 6) + (threadIdx.x >> 6);
  int lane = threadIdx.x & 63;
  if (wid >= n) return;
  float2 xv = ((const float2*)X)[(size_t)wid * 64 + lane];
  float2 v1 = ((const float2*)vs)[lane];
  float2 v2 = ((const float2*)vd)[lane];
  float ps = xv.x * v1.x + xv.y * v1.y;
  float pd = xv.x * v2.x + xv.y * v2.y;
  #pragma unroll
  for (int off = 32; off > 0; off >>= 1) {
    ps += __shfl_down(ps, off, 64);
    pd += __shfl_down(pd, off, 64);
  }
  if (lane == 0) { as_[wid] = ps; ad_[wid] = pd; }
}

// ---------------- GAT aggregation: one wave per dst node, 4 chains ----------------
// hs is bf16-packed (uint = 2 bf16). p computed inline from alpha gathers.
__global__ void gat_aggregate_kernel(const uint* __restrict__ hsb,
                                     const float* __restrict__ alpha_s,
                                     const float* __restrict__ alpha_d,
                                     const int* __restrict__ row_ptr,
                                     const int* __restrict__ src_sorted,
                                     const float* __restrict__ bias,
                                     float* __restrict__ out, int n) {
  int wid = blockIdx.x * (blockDim.x >> 6) + (threadIdx.x >> 6);
  int lane = threadIdx.x & 63;
  if (wid >= n) return;
  int beg = row_ptr[wid], end = row_ptr[wid + 1];
  float ad = alpha_d[wid];
  float s0 = 0.f, s1 = 0.f, s2 = 0.f, s3 = 0.f;
  float a0x = 0.f, a0y = 0.f, a1x = 0.f, a1y = 0.f;
  float a2x = 0.f, a2y = 0.f, a3x = 0.f, a3y = 0.f;
  int j = beg;
  for (; j + 4 <= end; j += 4) {
    int u0 = src_sorted[j + 0], u1 = src_sorted[j + 1];
    int u2 = src_sorted[j + 2], u3 = src_sorted[j + 3];
    float e0 = alpha_s[u0] + ad, e1 = alpha_s[u1] + ad;
    float e2 = alpha_s[u2] + ad, e3 = alpha_s[u3] + ad;
    e0 = (e0 > 0.f) ? e0 : 0.2f * e0;  e1 = (e1 > 0.f) ? e1 : 0.2f * e1;
    e2 = (e2 > 0.f) ? e2 : 0.2f * e2;  e3 = (e3 > 0.f) ? e3 : 0.2f * e3;
    float p0 = __expf(e0), p1 = __expf(e1), p2 = __expf(e2), p3 = __expf(e3);
    uint h0 = hsb[(size_t)u0 * 64 + lane];
    uint h1 = hsb[(size_t)u1 * 64 + lane];
    uint h2 = hsb[(size_t)u2 * 64 + lane];
    uint h3 = hsb[(size_t)u3 * 64 + lane];
    float h0x = __uint_as_float(h0 << 16), h0y = __uint_as_float(h0 & 0xFFFF0000u);
    float h1x = __uint_as_float(h1 << 16), h1y = __uint_as_float(h1 & 0xFFFF0000u);
    float h2x = __uint_as_float(h2 << 16), h2y = __uint_as_float(h2 & 0xFFFF0000u);
    float h3x = __uint_as_float(h3 << 16), h3y = __uint_as_float(h3 & 0xFFFF0000u);
    s0 += p0; a0x = fmaf(p0, h0x, a0x); a0y = fmaf(p0, h0y, a0y);
    s1 += p1; a1x = fmaf(p1, h1x, a1x); a1y = fmaf(p1, h1y, a1y);
    s2 += p2; a2x = fmaf(p2, h2x, a2x); a2y = fmaf(p2, h2y, a2y);
    s3 += p3; a3x = fmaf(p3, h3x, a3x); a3y = fmaf(p3, h3y, a3y);
  }
  for (; j < end; ++j) {
    int u0 = src_sorted[j];
    float e0 = alpha_s[u0] + ad;
    e0 = (e0 > 0.f) ? e0 : 0.2f * e0;
    float p0 = __expf(e0);
    uint h0 = hsb[(size_t)u0 * 64 + lane];
    float h0x = __uint_as_float(h0 << 16), h0y = __uint_as_float(h0 & 0xFFFF0000u);
    s0 += p0; a0x = fmaf(p0, h0x, a0x); a0y = fmaf(p0, h0y, a0y);
  }
  float s = (s0 + s1) + (s2 + s3);
  float ax = (a0x + a1x) + (a2x + a3x);
  float ay = (a0y + a1y) + (a2y + a3y);
  float inv = 1.f / (s + 1e-16f);
  float2 b = ((const float2*)bias)[lane];
  float o0 = fmaxf(fmaf(ax, inv, b.x), 0.f);
  float o1 = fmaxf(fmaf(ay, inv, b.y), 0.f);
  ((float2*)out)[(size_t)wid * 64 + lane] = make_float2(o0, o1);
}

// ---------------- fp32 GEMM, K=128 resident: C[N,M] = A[N,128] @ W[128,M] ----------------
// OBF16: store C as packed bf16 (ushort), else fp32.
template <int M, bool RELU, bool HASBIAS, bool OBF16>
__global__ __launch_bounds__(512, 1) void gemm_k128_kernel(const float* __restrict__ A,
                                                           const float* __restrict__ W,
                                                           const float* __restrict__ bias,
                                                           void* __restrict__ Cv, int n) {
  __shared__ float sA[128 * 128];
  __shared__ float sW[128 * M];
  const int t = threadIdx.x;
  const int row0 = blockIdx.x * 128;

  for (int i = t; i < (128 * M) / 4; i += 512)
    ((float4*)sW)[i] = ((const float4*)W)[i];
  for (int i = t; i < (128 * 128) / 4; i += 512) {
    int r = i >> 5, c = i & 31;
    int gr = row0 + r;
    float4 v = make_float4(0.f, 0.f, 0.f, 0.f);
    if (gr < n) v = ((const float4*)(A + (size_t)gr * 128))[c];
    ((float4*)(sA + r * 128))[c] = v;
  }
  __syncthreads();

  const int tx = t & 31;
  const int ty = t >> 5;         // 0..15 -> rows ty*8..ty*8+7
  constexpr int CPT = M / 32;    // 4 (M=128) or 2 (M=64)

  float acc[8][CPT];
  #pragma unroll
  for (int i = 0; i < 8; ++i)
    #pragma unroll
    for (int j = 0; j < CPT; ++j) acc[i][j] = 0.f;

  #pragma unroll 4
  for (int k = 0; k < 128; k += 4) {
    float a[8][4];
    #pragma unroll
    for (int i = 0; i < 8; ++i) {
      float4 av = *(const float4*)(sA + (ty * 8 + i) * 128 + k);
      a[i][0] = av.x; a[i][1] = av.y; a[i][2] = av.z; a[i][3] = av.w;
    }
    #pragma unroll
    for (int kk = 0; kk < 4; ++kk) {
      float w[CPT];
      if (CPT == 4) {
        float4 wv = *(const float4*)(sW + (k + kk) * M + tx * 4);
        w[0] = wv.x; w[1] = wv.y; w[2] = wv.z; w[3] = wv.w;
      } else {
        float2 wv = *(const float2*)(sW + (k + kk) * M + tx * 2);
        w[0] = wv.x; w[1] = wv.y;
      }
      #pragma unroll
      for (int i = 0; i < 8; ++i)
        #pragma unroll
        for (int j = 0; j < CPT; ++j) acc[i][j] = fmaf(a[i][kk], w[j], acc[i][j]);
    }
  }

  #pragma unroll
  for (int i = 0; i < 8; ++i) {
    int gr = row0 + ty * 8 + i;
    if (gr < n) {
      float v[CPT];
      #pragma unroll
      for (int j = 0; j < CPT; ++j) {
        v[j] = acc[i][j];
        if (HASBIAS) v[j] += bias[tx * CPT + j];
        if (RELU) v[j] = fmaxf(v[j], 0.f);
      }
      if (OBF16) {
        ushort* Cb = (ushort*)Cv;
        if (CPT == 4) {
          ushort4 o;
          o.x = f2bf_rne(v[0]); o.y = f2bf_rne(v[1]);
          o.z = f2bf_rne(v[2]); o.w = f2bf_rne(v[3]);
          *(ushort4*)(Cb + (size_t)gr * M + tx * CPT) = o;
        } else {
          ushort2 o;
          o.x = f2bf_rne(v[0]); o.y = f2bf_rne(v[1]);
          *(ushort2*)(Cb + (size_t)gr * M + tx * CPT) = o;
        }
      } else {
        float* C = (float*)Cv;
        #pragma unroll
        for (int j = 0; j < CPT; ++j) C[(size_t)gr * M + tx * CPT + j] = v[j];
      }
    }
  }
}

// ---------------------------------------------------------------------------
extern "C" void kernel_launch(void* const* d_in, const int* in_sizes, int n_in,
                              void* d_out, int out_size, void* d_ws, size_t ws_size,
                              hipStream_t stream) {
  const float* x     = (const float*)d_in[0];
  const int*   eidx  = (const int*)d_in[1];
  const float* W1s   = (const float*)d_in[2];
  const float* W1d   = (const float*)d_in[3];
  const float* a1s   = (const float*)d_in[4];
  const float* a1d   = (const float*)d_in[5];
  const float* b1    = (const float*)d_in[6];
  const float* W2    = (const float*)d_in[7];
  const float* a2s   = (const float*)d_in[8];
  const float* a2d   = (const float*)d_in[9];
  const float* b2    = (const float*)d_in[10];
  const float* W3    = (const float*)d_in[11];
  const float* a3s   = (const float*)d_in[12];
  const float* a3d   = (const float*)d_in[13];
  const float* b3    = (const float*)d_in[14];
  const float* Wl1   = (const float*)d_in[15];
  const float* bl1   = (const float*)d_in[16];
  const float* Wl2   = (const float*)d_in[17];
  const float* bl2   = (const float*)d_in[18];
  float* out = (float*)d_out;

  const int N = in_sizes[0] / 128;
  const int E = in_sizes[1] / 2;
  const int* src = eidx;
  const int* dst = eidx + E;

  // ---- workspace layout (512B aligned bump allocator) ----
  char* base = (char*)d_ws;
  size_t off = 0;
  auto alloc = [&](size_t bytes) -> void* {
    void* p = base + off;
    off += (bytes + 511) & ~(size_t)511;
    return p;
  };
  float* P        = (float*)alloc((size_t)N * 128 * 4);  // layer inputs/outputs, fp32
  uint*  Qb       = (uint*)alloc((size_t)N * 128 * 2);   // messages hs, packed bf16
  float* Q2       = (float*)alloc((size_t)N * 128 * 4);  // head hidden, fp32
  float* alpha_s  = (float*)alloc((size_t)N * 4);
  float* alpha_d  = (float*)alloc((size_t)N * 4);
  float* vs       = (float*)alloc(128 * 4);
  float* vd       = (float*)alloc(128 * 4);
  int* deg        = (int*)alloc((size_t)N * 4);
  int* row_ptr    = (int*)alloc((size_t)(N + 1) * 4);
  int* cursor     = (int*)alloc((size_t)N * 4);
  int* bsum       = (int*)alloc(128 * 4);
  int* boff       = (int*)alloc(128 * 4);
  int* src_sorted = (int*)alloc((size_t)E * 4);
  (void)ws_size;

  const int TB = 256;
  const int nwaveblk = (N + 3) / 4;          // 4 waves/block, 1 node/wave
  const int egrid = (E + TB - 1) / TB;
  const int ggrid = (N + 127) / 128;
  const int nb = (N + 1023) / 1024;          // <= 128

  // ---- CSR build (reused by all 3 layers) ----
  hipMemsetAsync(deg, 0, (size_t)N * 4, stream);
  count_deg_kernel<<<egrid, TB, 0, stream>>>(dst, deg, E);
  block_sum_kernel<<<nb, 1024, 0, stream>>>(deg, bsum, N);
  scan_bsum_kernel<<<1, 128, 0, stream>>>(bsum, boff, nb, row_ptr, N);
  block_exscan_kernel<<<nb, 1024, 0, stream>>>(deg, boff, row_ptr, cursor, N);
  fill_csr_kernel<<<egrid, TB, 0, stream>>>(src, dst, cursor, src_sorted, E);

  // ---- layer 1: x -> P ----
  make_v2_kernel<<<64, 256, 0, stream>>>(W1s, a1s, W1d, a1d, vs, vd);
  alpha_kernel<<<nwaveblk, TB, 0, stream>>>(x, vs, vd, alpha_s, alpha_d, N);
  gemm_k128_kernel<128, false, false, true><<<ggrid, 512, 0, stream>>>(x, W1s, nullptr, Qb, N);
  gat_aggregate_kernel<<<nwaveblk, TB, 0, stream>>>(Qb, alpha_s, alpha_d, row_ptr, src_sorted,
                                                    b1, P, N);

  // ---- layer 2: P -> P ----
  make_v2_kernel<<<64, 256, 0, stream>>>(W2, a2s, W2, a2d, vs, vd);
  alpha_kernel<<<nwaveblk, TB, 0, stream>>>(P, vs, vd, alpha_s, alpha_d, N);
  gemm_k128_kernel<128, false, false, true><<<ggrid, 512, 0, stream>>>(P, W2, nullptr, Qb, N);
  gat_aggregate_kernel<<<nwaveblk, TB, 0, stream>>>(Qb, alpha_s, alpha_d, row_ptr, src_sorted,
                                                    b2, P, N);

  // ---- layer 3: P -> P ----
  make_v2_kernel<<<64, 256, 0, stream>>>(W3, a3s, W3, a3d, vs, vd);
  alpha_kernel<<<nwaveblk, TB, 0, stream>>>(P, vs, vd, alpha_s, alpha_d, N);
  gemm_k128_kernel<128, false, false, true><<<ggrid, 512, 0, stream>>>(P, W3, nullptr, Qb, N);
  gat_aggregate_kernel<<<nwaveblk, TB, 0, stream>>>(Qb, alpha_s, alpha_d, row_ptr, src_sorted,
                                                    b3, P, N);

  // ---- MLP head ----
  gemm_k128_kernel<128, true, true, false><<<ggrid, 512, 0, stream>>>(P, Wl1, bl1, Q2, N);
  gemm_k128_kernel<64, false, true, false><<<ggrid, 512, 0, stream>>>(Q2, Wl2, bl2, out, N);
}

// Round 4
// 648.877 us; speedup vs baseline: 2.0369x; 1.2257x over previous
//
#include <hip/hip_runtime.h>
#include <hip/hip_bf16.h>
#include <cstdint>
#include <cstddef>

// ---------------------------------------------------------------------------
// GAT x3 + MLP head. fp32 compute; messages (GEMM output Q) stored bf16.
// CSR build = 2-level bucket sort (no random 4B scatters):
//   Phase A: chunk edges in LDS, coarse-bucket (512 dst/bucket) append in runs.
//   Phase B: per-bucket LDS counting sort -> coalesced row_ptr + src_sorted.
// ---------------------------------------------------------------------------

#define PA_CHUNK 4096
#define BKT_CAP  12288   // max edges per 512-node bucket (mean 8163, +45 sigma)

__device__ __forceinline__ ushort f2bf_rne(float f) {
  uint u = __float_as_uint(f);
  u += 0x7FFFu + ((u >> 16) & 1u);
  return (ushort)(u >> 16);
}

// ---------------- Phase A: scatter edges into coarse buckets ----------------
// rec = (src << 9) | (dst & 511); bucket = dst >> 9.  NB <= 256 required.
__global__ __launch_bounds__(256) void bucket_scatter_kernel(
    const int* __restrict__ src, const int* __restrict__ dst,
    int* __restrict__ bcount, uint* __restrict__ buckets, int E, int NB) {
  __shared__ int  hist[256];
  __shared__ int  base[256];
  __shared__ uint recs[PA_CHUNK];
  __shared__ ushort rb[PA_CHUNK];
  const int t = threadIdx.x;
  const int e0 = blockIdx.x * PA_CHUNK;
  const int nE = min(PA_CHUNK, E - e0);

  for (int i = t; i < 256; i += 256) hist[i] = 0;
  __syncthreads();
  for (int i = t; i < nE; i += 256) {
    int s = src[e0 + i], d = dst[e0 + i];
    int b = d >> 9;
    recs[i] = ((uint)s << 9) | (uint)(d & 511);
    rb[i] = (ushort)b;
    atomicAdd(&hist[b], 1);
  }
  __syncthreads();
  if (t < NB) base[t] = (hist[t] > 0) ? atomicAdd(&bcount[t], hist[t]) : 0;
  __syncthreads();
  for (int i = t; i < 256; i += 256) hist[i] = 0;
  __syncthreads();
  for (int i = t; i < nE; i += 256) {
    int b = rb[i];
    int r = atomicAdd(&hist[b], 1);
    int pos = base[b] + r;
    if (pos < BKT_CAP) buckets[(size_t)b * BKT_CAP + pos] = recs[i];
  }
}

// ---------------- scan bucket counts -> bucket bases (1 block) ----------------
__global__ __launch_bounds__(256) void scan_buckets_kernel(
    const int* __restrict__ bcount, int* __restrict__ bbase, int NB,
    int* __restrict__ row_ptr, int N, int E) {
  __shared__ int s[256];
  int t = threadIdx.x;
  int x = (t < NB) ? bcount[t] : 0;
  s[t] = x;
  __syncthreads();
  #pragma unroll
  for (int off = 1; off < 256; off <<= 1) {
    int v = (t >= off) ? s[t - off] : 0;
    __syncthreads();
    s[t] += v;
    __syncthreads();
  }
  if (t < NB) bbase[t] = s[t] - x;
  if (t == 0) row_ptr[N] = E;
}

// ---------------- Phase B: per-bucket counting sort ----------------
__global__ __launch_bounds__(256) void bucket_sort_kernel(
    const uint* __restrict__ buckets, const int* __restrict__ bcount,
    const int* __restrict__ bbase, int* __restrict__ row_ptr,
    int* __restrict__ src_sorted, int N) {
  const int b = blockIdx.x;
  const int t = threadIdx.x;
  __shared__ int h[512], o[512], c[512];
  __shared__ int wsum[4];
  const int cnt = min(bcount[b], BKT_CAP);
  const int gbase = bbase[b];
  const uint* rec = buckets + (size_t)b * BKT_CAP;

  for (int i = t; i < 512; i += 256) { h[i] = 0; c[i] = 0; }
  __syncthreads();
  for (int i = t; i < cnt; i += 256) atomicAdd(&h[rec[i] & 511], 1);
  __syncthreads();

  // exclusive scan of h[0..511] with 256 threads (pairs + wave scan)
  int a0 = h[2 * t], a1 = h[2 * t + 1];
  int s2 = a0 + a1;
  int lane = t & 63, w = t >> 6;
  int v = s2;
  #pragma unroll
  for (int off = 1; off < 64; off <<= 1) {
    int u = __shfl_up(v, off, 64);
    if (lane >= off) v += u;
  }
  if (lane == 63) wsum[w] = v;
  __syncthreads();
  int woff = 0;
  for (int i = 0; i < w; ++i) woff += wsum[i];
  int excl = (v - s2) + woff;
  o[2 * t]     = excl;
  o[2 * t + 1] = excl + a0;
  __syncthreads();

  // row_ptr for this bucket's 512 nodes
  #pragma unroll
  for (int i = t; i < 512; i += 256) {
    int node = (b << 9) + i;
    if (node < N) row_ptr[node] = gbase + o[i];
  }

  // scatter srcs into their final (contiguous, L2-resident) slots
  for (int i = t; i < cnt; i += 256) {
    uint r = rec[i];
    int d9 = r & 511;
    int rk = atomicAdd(&c[d9], 1);
    src_sorted[gbase + o[d9] + rk] = (int)(r >> 9);
  }
}

// ---------------- vs = Wsrc @ a_s, vd = Wdst @ a_d (one wave per output) ----------------
__global__ void make_v2_kernel(const float* __restrict__ Ws, const float* __restrict__ as_,
                               const float* __restrict__ Wd, const float* __restrict__ ad_,
                               float* __restrict__ vs, float* __restrict__ vd) {
  int gw = blockIdx.x * (blockDim.x >> 6) + (threadIdx.x >> 6);  // 0..255
  int lane = threadIdx.x & 63;
  int d = gw & 127;
  const float* W = (gw < 128) ? Ws : Wd;
  const float* a = (gw < 128) ? as_ : ad_;
  float2 w0 = ((const float2*)(W + d * 128))[lane];
  float2 a0 = ((const float2*)a)[lane];
  float p = w0.x * a0.x + w0.y * a0.y;
  #pragma unroll
  for (int off = 32; off >= 1; off >>= 1) p += __shfl_down(p, off, 64);
  if (lane == 0) ((gw < 128) ? vs : vd)[d] = p;
}

// ---------------- alpha_s / alpha_d: per-node dot(X_row, v), X fp32 ----------------
__global__ void alpha_kernel(const float* __restrict__ X, const float* __restrict__ vs,
                             const float* __restrict__ vd, float* __restrict__ as_,
                             float* __restrict__ ad_, int n) {
  int wid = blockIdx.x * (blockDim.x >> 6) + (threadIdx.x >> 6);
  int lane = threadIdx.x & 63;
  if (wid >= n) return;
  float2 xv = ((const float2*)X)[(size_t)wid * 64 + lane];
  float2 v1 = ((const float2*)vs)[lane];
  float2 v2 = ((const float2*)vd)[lane];
  float ps = xv.x * v1.x + xv.y * v1.y;
  float pd = xv.x * v2.x + xv.y * v2.y;
  #pragma unroll
  for (int off = 32; off > 0; off >>= 1) {
    ps += __shfl_down(ps, off, 64);
    pd += __shfl_down(pd, off, 64);
  }
  if (lane == 0) { as_[wid] = ps; ad_[wid] = pd; }
}

// ---------------- GAT aggregation: one wave per dst node, 4 chains ----------------
__global__ void gat_aggregate_kernel(const uint* __restrict__ hsb,
                                     const float* __restrict__ alpha_s,
                                     const float* __restrict__ alpha_d,
                                     const int* __restrict__ row_ptr,
                                     const int* __restrict__ src_sorted,
                                     const float* __restrict__ bias,
                                     float* __restrict__ out, int n) {
  int wid = blockIdx.x * (blockDim.x >> 6) + (threadIdx.x >> 6);
  int lane = threadIdx.x & 63;
  if (wid >= n) return;
  int beg = row_ptr[wid], end = row_ptr[wid + 1];
  float ad = alpha_d[wid];
  float s0 = 0.f, s1 = 0.f, s2 = 0.f, s3 = 0.f;
  float a0x = 0.f, a0y = 0.f, a1x = 0.f, a1y = 0.f;
  float a2x = 0.f, a2y = 0.f, a3x = 0.f, a3y = 0.f;
  int j = beg;
  for (; j + 4 <= end; j += 4) {
    int u0 = src_sorted[j + 0], u1 = src_sorted[j + 1];
    int u2 = src_sorted[j + 2], u3 = src_sorted[j + 3];
    float e0 = alpha_s[u0] + ad, e1 = alpha_s[u1] + ad;
    float e2 = alpha_s[u2] + ad, e3 = alpha_s[u3] + ad;
    e0 = (e0 > 0.f) ? e0 : 0.2f * e0;  e1 = (e1 > 0.f) ? e1 : 0.2f * e1;
    e2 = (e2 > 0.f) ? e2 : 0.2f * e2;  e3 = (e3 > 0.f) ? e3 : 0.2f * e3;
    float p0 = __expf(e0), p1 = __expf(e1), p2 = __expf(e2), p3 = __expf(e3);
    uint h0 = hsb[(size_t)u0 * 64 + lane];
    uint h1 = hsb[(size_t)u1 * 64 + lane];
    uint h2 = hsb[(size_t)u2 * 64 + lane];
    uint h3 = hsb[(size_t)u3 * 64 + lane];
    float h0x = __uint_as_float(h0 << 16), h0y = __uint_as_float(h0 & 0xFFFF0000u);
    float h1x = __uint_as_float(h1 << 16), h1y = __uint_as_float(h1 & 0xFFFF0000u);
    float h2x = __uint_as_float(h2 << 16), h2y = __uint_as_float(h2 & 0xFFFF0000u);
    float h3x = __uint_as_float(h3 << 16), h3y = __uint_as_float(h3 & 0xFFFF0000u);
    s0 += p0; a0x = fmaf(p0, h0x, a0x); a0y = fmaf(p0, h0y, a0y);
    s1 += p1; a1x = fmaf(p1, h1x, a1x); a1y = fmaf(p1, h1y, a1y);
    s2 += p2; a2x = fmaf(p2, h2x, a2x); a2y = fmaf(p2, h2y, a2y);
    s3 += p3; a3x = fmaf(p3, h3x, a3x); a3y = fmaf(p3, h3y, a3y);
  }
  for (; j < end; ++j) {
    int u0 = src_sorted[j];
    float e0 = alpha_s[u0] + ad;
    e0 = (e0 > 0.f) ? e0 : 0.2f * e0;
    float p0 = __expf(e0);
    uint h0 = hsb[(size_t)u0 * 64 + lane];
    float h0x = __uint_as_float(h0 << 16), h0y = __uint_as_float(h0 & 0xFFFF0000u);
    s0 += p0; a0x = fmaf(p0, h0x, a0x); a0y = fmaf(p0, h0y, a0y);
  }
  float s = (s0 + s1) + (s2 + s3);
  float ax = (a0x + a1x) + (a2x + a3x);
  float ay = (a0y + a1y) + (a2y + a3y);
  float inv = 1.f / (s + 1e-16f);
  float2 b = ((const float2*)bias)[lane];
  float o0 = fmaxf(fmaf(ax, inv, b.x), 0.f);
  float o1 = fmaxf(fmaf(ay, inv, b.y), 0.f);
  ((float2*)out)[(size_t)wid * 64 + lane] = make_float2(o0, o1);
}

// ---------------- fp32 GEMM, K=128 resident: C[N,M] = A[N,128] @ W[128,M] ----------------
template <int M, bool RELU, bool HASBIAS, bool OBF16>
__global__ __launch_bounds__(512, 1) void gemm_k128_kernel(const float* __restrict__ A,
                                                           const float* __restrict__ W,
                                                           const float* __restrict__ bias,
                                                           void* __restrict__ Cv, int n) {
  __shared__ float sA[128 * 128];
  __shared__ float sW[128 * M];
  const int t = threadIdx.x;
  const int row0 = blockIdx.x * 128;

  for (int i = t; i < (128 * M) / 4; i += 512)
    ((float4*)sW)[i] = ((const float4*)W)[i];
  for (int i = t; i < (128 * 128) / 4; i += 512) {
    int r = i >> 5, c = i & 31;
    int gr = row0 + r;
    float4 v = make_float4(0.f, 0.f, 0.f, 0.f);
    if (gr < n) v = ((const float4*)(A + (size_t)gr * 128))[c];
    ((float4*)(sA + r * 128))[c] = v;
  }
  __syncthreads();

  const int tx = t & 31;
  const int ty = t >> 5;
  constexpr int CPT = M / 32;

  float acc[8][CPT];
  #pragma unroll
  for (int i = 0; i < 8; ++i)
    #pragma unroll
    for (int j = 0; j < CPT; ++j) acc[i][j] = 0.f;

  #pragma unroll 4
  for (int k = 0; k < 128; k += 4) {
    float a[8][4];
    #pragma unroll
    for (int i = 0; i < 8; ++i) {
      float4 av = *(const float4*)(sA + (ty * 8 + i) * 128 + k);
      a[i][0] = av.x; a[i][1] = av.y; a[i][2] = av.z; a[i][3] = av.w;
    }
    #pragma unroll
    for (int kk = 0; kk < 4; ++kk) {
      float w[CPT];
      if (CPT == 4) {
        float4 wv = *(const float4*)(sW + (k + kk) * M + tx * 4);
        w[0] = wv.x; w[1] = wv.y; w[2] = wv.z; w[3] = wv.w;
      } else {
        float2 wv = *(const float2*)(sW + (k + kk) * M + tx * 2);
        w[0] = wv.x; w[1] = wv.y;
      }
      #pragma unroll
      for (int i = 0; i < 8; ++i)
        #pragma unroll
        for (int j = 0; j < CPT; ++j) acc[i][j] = fmaf(a[i][kk], w[j], acc[i][j]);
    }
  }

  #pragma unroll
  for (int i = 0; i < 8; ++i) {
    int gr = row0 + ty * 8 + i;
    if (gr < n) {
      float v[CPT];
      #pragma unroll
      for (int j = 0; j < CPT; ++j) {
        v[j] = acc[i][j];
        if (HASBIAS) v[j] += bias[tx * CPT + j];
        if (RELU) v[j] = fmaxf(v[j], 0.f);
      }
      if (OBF16) {
        ushort* Cb = (ushort*)Cv;
        if (CPT == 4) {
          ushort4 o;
          o.x = f2bf_rne(v[0]); o.y = f2bf_rne(v[1]);
          o.z = f2bf_rne(v[2]); o.w = f2bf_rne(v[3]);
          *(ushort4*)(Cb + (size_t)gr * M + tx * CPT) = o;
        } else {
          ushort2 o;
          o.x = f2bf_rne(v[0]); o.y = f2bf_rne(v[1]);
          *(ushort2*)(Cb + (size_t)gr * M + tx * CPT) = o;
        }
      } else {
        float* C = (float*)Cv;
        #pragma unroll
        for (int j = 0; j < CPT; ++j) C[(size_t)gr * M + tx * CPT + j] = v[j];
      }
    }
  }
}

// ---------------------------------------------------------------------------
extern "C" void kernel_launch(void* const* d_in, const int* in_sizes, int n_in,
                              void* d_out, int out_size, void* d_ws, size_t ws_size,
                              hipStream_t stream) {
  const float* x     = (const float*)d_in[0];
  const int*   eidx  = (const int*)d_in[1];
  const float* W1s   = (const float*)d_in[2];
  const float* W1d   = (const float*)d_in[3];
  const float* a1s   = (const float*)d_in[4];
  const float* a1d   = (const float*)d_in[5];
  const float* b1    = (const float*)d_in[6];
  const float* W2    = (const float*)d_in[7];
  const float* a2s   = (const float*)d_in[8];
  const float* a2d   = (const float*)d_in[9];
  const float* b2    = (const float*)d_in[10];
  const float* W3    = (const float*)d_in[11];
  const float* a3s   = (const float*)d_in[12];
  const float* a3d   = (const float*)d_in[13];
  const float* b3    = (const float*)d_in[14];
  const float* Wl1   = (const float*)d_in[15];
  const float* bl1   = (const float*)d_in[16];
  const float* Wl2   = (const float*)d_in[17];
  const float* bl2   = (const float*)d_in[18];
  float* out = (float*)d_out;

  const int N = in_sizes[0] / 128;
  const int E = in_sizes[1] / 2;
  const int* src = eidx;
  const int* dst = eidx + E;
  const int NB = (N + 511) >> 9;             // coarse buckets (<=256 for N<=131072)

  // ---- workspace layout (512B aligned bump allocator) ----
  char* base = (char*)d_ws;
  size_t off = 0;
  auto alloc = [&](size_t bytes) -> void* {
    void* p = base + off;
    off += (bytes + 511) & ~(size_t)511;
    return p;
  };
  float* P        = (float*)alloc((size_t)N * 128 * 4);  // layer inputs/outputs, fp32
  uint*  Qb       = (uint*)alloc((size_t)N * 128 * 2);   // messages hs, packed bf16
  float* Q2       = (float*)alloc((size_t)N * 128 * 4);  // head hidden, fp32
  uint*  buckets  = (uint*)Q2;                           // ALIAS: dead before head GEMMs
  float* alpha_s  = (float*)alloc((size_t)N * 4);
  float* alpha_d  = (float*)alloc((size_t)N * 4);
  float* vs       = (float*)alloc(128 * 4);
  float* vd       = (float*)alloc(128 * 4);
  int* row_ptr    = (int*)alloc((size_t)(N + 1) * 4);
  int* bcount     = (int*)alloc(256 * 4);
  int* bbase      = (int*)alloc(256 * 4);
  int* src_sorted = (int*)alloc((size_t)E * 4);
  (void)ws_size;

  const int TB = 256;
  const int nwaveblk = (N + 3) / 4;
  const int ggrid = (N + 127) / 128;
  const int pagrid = (E + PA_CHUNK - 1) / PA_CHUNK;

  // ---- CSR build via 2-level bucket sort ----
  hipMemsetAsync(bcount, 0, 256 * 4, stream);
  bucket_scatter_kernel<<<pagrid, 256, 0, stream>>>(src, dst, bcount, buckets, E, NB);
  scan_buckets_kernel<<<1, 256, 0, stream>>>(bcount, bbase, NB, row_ptr, N, E);
  bucket_sort_kernel<<<NB, 256, 0, stream>>>(buckets, bcount, bbase, row_ptr, src_sorted, N);

  // ---- layer 1: x -> P ----
  make_v2_kernel<<<64, 256, 0, stream>>>(W1s, a1s, W1d, a1d, vs, vd);
  alpha_kernel<<<nwaveblk, TB, 0, stream>>>(x, vs, vd, alpha_s, alpha_d, N);
  gemm_k128_kernel<128, false, false, true><<<ggrid, 512, 0, stream>>>(x, W1s, nullptr, Qb, N);
  gat_aggregate_kernel<<<nwaveblk, TB, 0, stream>>>(Qb, alpha_s, alpha_d, row_ptr, src_sorted,
                                                    b1, P, N);

  // ---- layer 2: P -> P ----
  make_v2_kernel<<<64, 256, 0, stream>>>(W2, a2s, W2, a2d, vs, vd);
  alpha_kernel<<<nwaveblk, TB, 0, stream>>>(P, vs, vd, alpha_s, alpha_d, N);
  gemm_k128_kernel<128, false, false, true><<<ggrid, 512, 0, stream>>>(P, W2, nullptr, Qb, N);
  gat_aggregate_kernel<<<nwaveblk, TB, 0, stream>>>(Qb, alpha_s, alpha_d, row_ptr, src_sorted,
                                                    b2, P, N);

  // ---- layer 3: P -> P ----
  make_v2_kernel<<<64, 256, 0, stream>>>(W3, a3s, W3, a3d, vs, vd);
  alpha_kernel<<<nwaveblk, TB, 0, stream>>>(P, vs, vd, alpha_s, alpha_d, N);
  gemm_k128_kernel<128, false, false, true><<<ggrid, 512, 0, stream>>>(P, W3, nullptr, Qb, N);
  gat_aggregate_kernel<<<nwaveblk, TB, 0, stream>>>(Qb, alpha_s, alpha_d, row_ptr, src_sorted,
                                                    b3, P, N);

  // ---- MLP head (Q2 overwrites the now-dead bucket region) ----
  gemm_k128_kernel<128, true, true, false><<<ggrid, 512, 0, stream>>>(P, Wl1, bl1, Q2, N);
  gemm_k128_kernel<64, false, true, false><<<ggrid, 512, 0, stream>>>(Q2, Wl2, bl2, out, N);
}

// Round 5
// 467.775 us; speedup vs baseline: 2.8255x; 1.3872x over previous
//
#include <hip/hip_runtime.h>
#include <hip/hip_bf16.h>
#include <cstdint>
#include <cstddef>

// ---------------------------------------------------------------------------
// GAT x3 + MLP head.
// GEMMs: MFMA bf16 (fp32 accum), 128xTN block tile, XOR-swizzled LDS.
// Aggregation: CSR-by-dst; per-edge softmax numerators precomputed (edge_p);
// inner loop = pure gather+FMA with 4 independent chains.
// CSR build = 2-level bucket sort (R4).
// ---------------------------------------------------------------------------

#define PA_CHUNK 4096
#define BKT_CAP  12288

using short8  = __attribute__((ext_vector_type(8))) short;
using ushort8 = __attribute__((ext_vector_type(8))) unsigned short;
using f32x4   = __attribute__((ext_vector_type(4))) float;

__device__ __forceinline__ ushort f2bf_rne(float f) {
  uint u = __float_as_uint(f);
  u += 0x7FFFu + ((u >> 16) & 1u);
  return (ushort)(u >> 16);
}

// ---------------- Phase A: scatter edges into coarse buckets ----------------
__global__ __launch_bounds__(256) void bucket_scatter_kernel(
    const int* __restrict__ src, const int* __restrict__ dst,
    int* __restrict__ bcount, uint* __restrict__ buckets, int E, int NB) {
  __shared__ int  hist[256];
  __shared__ int  base[256];
  __shared__ uint recs[PA_CHUNK];
  __shared__ ushort rb[PA_CHUNK];
  const int t = threadIdx.x;
  const int e0 = blockIdx.x * PA_CHUNK;
  const int nE = min(PA_CHUNK, E - e0);

  for (int i = t; i < 256; i += 256) hist[i] = 0;
  __syncthreads();
  for (int i = t; i < nE; i += 256) {
    int s = src[e0 + i], d = dst[e0 + i];
    int b = d >> 9;
    recs[i] = ((uint)s << 9) | (uint)(d & 511);
    rb[i] = (ushort)b;
    atomicAdd(&hist[b], 1);
  }
  __syncthreads();
  if (t < NB) base[t] = (hist[t] > 0) ? atomicAdd(&bcount[t], hist[t]) : 0;
  __syncthreads();
  for (int i = t; i < 256; i += 256) hist[i] = 0;
  __syncthreads();
  for (int i = t; i < nE; i += 256) {
    int b = rb[i];
    int r = atomicAdd(&hist[b], 1);
    int pos = base[b] + r;
    if (pos < BKT_CAP) buckets[(size_t)b * BKT_CAP + pos] = recs[i];
  }
}

__global__ __launch_bounds__(256) void scan_buckets_kernel(
    const int* __restrict__ bcount, int* __restrict__ bbase, int NB,
    int* __restrict__ row_ptr, int N, int E) {
  __shared__ int s[256];
  int t = threadIdx.x;
  int x = (t < NB) ? bcount[t] : 0;
  s[t] = x;
  __syncthreads();
  #pragma unroll
  for (int off = 1; off < 256; off <<= 1) {
    int v = (t >= off) ? s[t - off] : 0;
    __syncthreads();
    s[t] += v;
    __syncthreads();
  }
  if (t < NB) bbase[t] = s[t] - x;
  if (t == 0) row_ptr[N] = E;
}

__global__ __launch_bounds__(256) void bucket_sort_kernel(
    const uint* __restrict__ buckets, const int* __restrict__ bcount,
    const int* __restrict__ bbase, int* __restrict__ row_ptr,
    int* __restrict__ src_sorted, int N) {
  const int b = blockIdx.x;
  const int t = threadIdx.x;
  __shared__ int h[512], o[512], c[512];
  __shared__ int wsum[4];
  const int cnt = min(bcount[b], BKT_CAP);
  const int gbase = bbase[b];
  const uint* rec = buckets + (size_t)b * BKT_CAP;

  for (int i = t; i < 512; i += 256) { h[i] = 0; c[i] = 0; }
  __syncthreads();
  for (int i = t; i < cnt; i += 256) atomicAdd(&h[rec[i] & 511], 1);
  __syncthreads();

  int a0 = h[2 * t], a1 = h[2 * t + 1];
  int s2 = a0 + a1;
  int lane = t & 63, w = t >> 6;
  int v = s2;
  #pragma unroll
  for (int off = 1; off < 64; off <<= 1) {
    int u = __shfl_up(v, off, 64);
    if (lane >= off) v += u;
  }
  if (lane == 63) wsum[w] = v;
  __syncthreads();
  int woff = 0;
  for (int i = 0; i < w; ++i) woff += wsum[i];
  int excl = (v - s2) + woff;
  o[2 * t]     = excl;
  o[2 * t + 1] = excl + a0;
  __syncthreads();

  for (int i = t; i < 512; i += 256) {
    int node = (b << 9) + i;
    if (node < N) row_ptr[node] = gbase + o[i];
  }
  for (int i = t; i < cnt; i += 256) {
    uint r = rec[i];
    int d9 = r & 511;
    int rk = atomicAdd(&c[d9], 1);
    src_sorted[gbase + o[d9] + rk] = (int)(r >> 9);
  }
}

// ---------------- weight prep: Wt_swz bf16, transposed + XOR-swizzled ----------------
// W: [128 x TN] fp32 row-major.  Wt layout: row n (0..TN-1), 16 chunks of 8 bf16;
// chunk c stored at position (c ^ (n & 7)); element j of chunk = W[(c*8+j)][n].
__global__ __launch_bounds__(256) void wprep_kernel(const float* __restrict__ W,
                                                    ushort* __restrict__ Wt, int TN) {
  int idx = blockIdx.x * 256 + threadIdx.x;       // TN*16 total
  if (idx >= TN * 16) return;
  int n = idx % TN;
  int c = idx / TN;
  ushort8 o;
  #pragma unroll
  for (int j = 0; j < 8; ++j) o[j] = f2bf_rne(W[(c * 8 + j) * TN + n]);
  *(ushort8*)(Wt + n * 128 + ((c ^ (n & 7)) * 8)) = o;
}

// ---------------- MFMA GEMM: C[N,TN] = A[N,128] @ W[128,TN] ----------------
template <int TN, bool RELU, bool HASBIAS, bool OBF16>
__global__ __launch_bounds__(256) void mfma_gemm_kernel(const float* __restrict__ A,
                                                        const ushort* __restrict__ Wt,
                                                        const float* __restrict__ bias,
                                                        void* __restrict__ Cv, int n) {
  constexpr int WCOLS = TN / 2;       // per-wave cols (2x2 wave grid)
  constexpr int FI = 4;               // 64 rows / 16
  constexpr int FJ = WCOLS / 16;      // 4 (TN=128) or 2 (TN=64)
  __shared__ char lds[32768 + TN * 256];
  ushort* sA = (ushort*)lds;                    // [128 rows][16 chunks of 8 bf16]
  ushort* sW = (ushort*)(lds + 32768);          // [TN rows][16 chunks]

  const int t = threadIdx.x;
  const int row0 = blockIdx.x * 128;
  const int lane = t & 63;
  const int wid = t >> 6;
  const int wr = wid >> 1, wc = wid & 1;

  // stage A (fp32 -> bf16, swizzled 16B chunks)
  #pragma unroll
  for (int i = 0; i < 8; ++i) {
    int r = i * 16 + (t >> 4);
    int c = t & 15;
    int gr = row0 + r;
    float4 v0 = make_float4(0.f, 0.f, 0.f, 0.f), v1 = v0;
    if (gr < n) {
      const float4* Ar = (const float4*)(A + (size_t)gr * 128);
      v0 = Ar[c * 2];
      v1 = Ar[c * 2 + 1];
    }
    ushort8 o;
    o[0] = f2bf_rne(v0.x); o[1] = f2bf_rne(v0.y); o[2] = f2bf_rne(v0.z); o[3] = f2bf_rne(v0.w);
    o[4] = f2bf_rne(v1.x); o[5] = f2bf_rne(v1.y); o[6] = f2bf_rne(v1.z); o[7] = f2bf_rne(v1.w);
    *(ushort8*)(sA + r * 128 + ((c ^ (r & 7)) * 8)) = o;
  }
  // stage W (already bf16 + swizzled in global)
  #pragma unroll
  for (int i = 0; i < TN / 16; ++i) {
    int chunk = i * 256 + t;
    *(ushort8*)(sW + chunk * 8) = *(const ushort8*)(Wt + chunk * 8);
  }
  __syncthreads();

  f32x4 acc[FI][FJ] = {};
  const int lm = lane & 15, q = lane >> 4, l7 = lane & 7;

  #pragma unroll
  for (int kk = 0; kk < 4; ++kk) {
    const int cs = kk * 4 + q;
    short8 af[FI], bfr[FJ];
    #pragma unroll
    for (int i = 0; i < FI; ++i) {
      int r = wr * 64 + i * 16 + lm;
      af[i] = *(const short8*)(sA + r * 128 + ((cs ^ l7) * 8));
    }
    #pragma unroll
    for (int j = 0; j < FJ; ++j) {
      int nn = wc * WCOLS + j * 16 + lm;
      bfr[j] = *(const short8*)(sW + nn * 128 + ((cs ^ l7) * 8));
    }
    #pragma unroll
    for (int i = 0; i < FI; ++i)
      #pragma unroll
      for (int j = 0; j < FJ; ++j)
        acc[i][j] = __builtin_amdgcn_mfma_f32_16x16x32_bf16(af[i], bfr[j], acc[i][j], 0, 0, 0);
  }

  // write C: col = lane&15, row = (lane>>4)*4 + reg
  #pragma unroll
  for (int i = 0; i < FI; ++i) {
    #pragma unroll
    for (int j = 0; j < FJ; ++j) {
      int gcol = wc * WCOLS + j * 16 + lm;
      float bv = HASBIAS ? bias[gcol] : 0.f;
      #pragma unroll
      for (int r = 0; r < 4; ++r) {
        int grow = row0 + wr * 64 + i * 16 + q * 4 + r;
        if (grow < n) {
          float v = acc[i][j][r] + bv;
          if (RELU) v = fmaxf(v, 0.f);
          if (OBF16) ((ushort*)Cv)[(size_t)grow * TN + gcol] = f2bf_rne(v);
          else       ((float*)Cv)[(size_t)grow * TN + gcol] = v;
        }
      }
    }
  }
}

// ---------------- vs/vd = W @ a (layer 1 dst path) ----------------
__global__ void make_v2_kernel(const float* __restrict__ Ws, const float* __restrict__ as_,
                               const float* __restrict__ Wd, const float* __restrict__ ad_,
                               float* __restrict__ vs, float* __restrict__ vd) {
  int gw = blockIdx.x * (blockDim.x >> 6) + (threadIdx.x >> 6);
  int lane = threadIdx.x & 63;
  int d = gw & 127;
  const float* W = (gw < 128) ? Ws : Wd;
  const float* a = (gw < 128) ? as_ : ad_;
  float2 w0 = ((const float2*)(W + d * 128))[lane];
  float2 a0 = ((const float2*)a)[lane];
  float p = w0.x * a0.x + w0.y * a0.y;
  #pragma unroll
  for (int off = 32; off >= 1; off >>= 1) p += __shfl_down(p, off, 64);
  if (lane == 0) ((gw < 128) ? vs : vd)[d] = p;
}

// ---------------- alpha from fp32 X (layer 1) ----------------
__global__ void alpha_kernel(const float* __restrict__ X, const float* __restrict__ vs,
                             const float* __restrict__ vd, float* __restrict__ as_,
                             float* __restrict__ ad_, int n) {
  int wid = blockIdx.x * (blockDim.x >> 6) + (threadIdx.x >> 6);
  int lane = threadIdx.x & 63;
  if (wid >= n) return;
  float2 xv = ((const float2*)X)[(size_t)wid * 64 + lane];
  float2 v1 = ((const float2*)vs)[lane];
  float2 v2 = ((const float2*)vd)[lane];
  float ps = xv.x * v1.x + xv.y * v1.y;
  float pd = xv.x * v2.x + xv.y * v2.y;
  #pragma unroll
  for (int off = 32; off > 0; off >>= 1) {
    ps += __shfl_down(ps, off, 64);
    pd += __shfl_down(pd, off, 64);
  }
  if (lane == 0) { as_[wid] = ps; ad_[wid] = pd; }
}

// ---------------- alpha from bf16 hs (layers 2,3): as = hs@a_s, ad = hs@a_d ----------------
__global__ void alphaQ_kernel(const uint* __restrict__ hsb, const float* __restrict__ a_s,
                              const float* __restrict__ a_d, float* __restrict__ as_,
                              float* __restrict__ ad_, int n) {
  int wid = blockIdx.x * (blockDim.x >> 6) + (threadIdx.x >> 6);
  int lane = threadIdx.x & 63;
  if (wid >= n) return;
  uint h = hsb[(size_t)wid * 64 + lane];
  float hx = __uint_as_float(h << 16), hy = __uint_as_float(h & 0xFFFF0000u);
  float2 s2 = ((const float2*)a_s)[lane];
  float2 d2 = ((const float2*)a_d)[lane];
  float ps = hx * s2.x + hy * s2.y;
  float pd = hx * d2.x + hy * d2.y;
  #pragma unroll
  for (int off = 32; off > 0; off >>= 1) {
    ps += __shfl_down(ps, off, 64);
    pd += __shfl_down(pd, off, 64);
  }
  if (lane == 0) { as_[wid] = ps; ad_[wid] = pd; }
}

// ---------------- per-edge p = exp(leaky_relu(as[src]+ad[dst])), CSR order ----------------
__global__ void edge_p_kernel(const int* __restrict__ row_ptr, const int* __restrict__ src_sorted,
                              const float* __restrict__ alpha_s, const float* __restrict__ alpha_d,
                              float* __restrict__ p_sorted, int n) {
  int wid = blockIdx.x * (blockDim.x >> 6) + (threadIdx.x >> 6);
  int lane = threadIdx.x & 63;
  int node = wid * 4 + (lane >> 4);
  if (node >= n) return;
  int beg = row_ptr[node], end = row_ptr[node + 1];
  float ad = alpha_d[node];
  for (int j = beg + (lane & 15); j < end; j += 16) {
    float e = alpha_s[src_sorted[j]] + ad;
    e = (e > 0.f) ? e : 0.2f * e;
    p_sorted[j] = __expf(e);
  }
}

// ---------------- GAT aggregation: one wave per dst node, 4 chains ----------------
__global__ void gat_aggregate_kernel(const uint* __restrict__ hsb,
                                     const float* __restrict__ p_sorted,
                                     const int* __restrict__ row_ptr,
                                     const int* __restrict__ src_sorted,
                                     const float* __restrict__ bias,
                                     float* __restrict__ out, int n) {
  int wid = blockIdx.x * (blockDim.x >> 6) + (threadIdx.x >> 6);
  int lane = threadIdx.x & 63;
  if (wid >= n) return;
  int beg = row_ptr[wid], end = row_ptr[wid + 1];
  float s0 = 0.f, s1 = 0.f, s2 = 0.f, s3 = 0.f;
  float a0x = 0.f, a0y = 0.f, a1x = 0.f, a1y = 0.f;
  float a2x = 0.f, a2y = 0.f, a3x = 0.f, a3y = 0.f;
  int j = beg;
  for (; j + 4 <= end; j += 4) {
    int u0 = src_sorted[j + 0], u1 = src_sorted[j + 1];
    int u2 = src_sorted[j + 2], u3 = src_sorted[j + 3];
    float p0 = p_sorted[j + 0], p1 = p_sorted[j + 1];
    float p2 = p_sorted[j + 2], p3 = p_sorted[j + 3];
    uint h0 = hsb[(size_t)u0 * 64 + lane];
    uint h1 = hsb[(size_t)u1 * 64 + lane];
    uint h2 = hsb[(size_t)u2 * 64 + lane];
    uint h3 = hsb[(size_t)u3 * 64 + lane];
    s0 += p0; a0x = fmaf(p0, __uint_as_float(h0 << 16), a0x); a0y = fmaf(p0, __uint_as_float(h0 & 0xFFFF0000u), a0y);
    s1 += p1; a1x = fmaf(p1, __uint_as_float(h1 << 16), a1x); a1y = fmaf(p1, __uint_as_float(h1 & 0xFFFF0000u), a1y);
    s2 += p2; a2x = fmaf(p2, __uint_as_float(h2 << 16), a2x); a2y = fmaf(p2, __uint_as_float(h2 & 0xFFFF0000u), a2y);
    s3 += p3; a3x = fmaf(p3, __uint_as_float(h3 << 16), a3x); a3y = fmaf(p3, __uint_as_float(h3 & 0xFFFF0000u), a3y);
  }
  for (; j < end; ++j) {
    int u0 = src_sorted[j];
    float p0 = p_sorted[j];
    uint h0 = hsb[(size_t)u0 * 64 + lane];
    s0 += p0; a0x = fmaf(p0, __uint_as_float(h0 << 16), a0x); a0y = fmaf(p0, __uint_as_float(h0 & 0xFFFF0000u), a0y);
  }
  float s = (s0 + s1) + (s2 + s3);
  float ax = (a0x + a1x) + (a2x + a3x);
  float ay = (a0y + a1y) + (a2y + a3y);
  float inv = 1.f / (s + 1e-16f);
  float2 b = ((const float2*)bias)[lane];
  float o0 = fmaxf(fmaf(ax, inv, b.x), 0.f);
  float o1 = fmaxf(fmaf(ay, inv, b.y), 0.f);
  ((float2*)out)[(size_t)wid * 64 + lane] = make_float2(o0, o1);
}

// ---------------------------------------------------------------------------
extern "C" void kernel_launch(void* const* d_in, const int* in_sizes, int n_in,
                              void* d_out, int out_size, void* d_ws, size_t ws_size,
                              hipStream_t stream) {
  const float* x     = (const float*)d_in[0];
  const int*   eidx  = (const int*)d_in[1];
  const float* W1s   = (const float*)d_in[2];
  const float* W1d   = (const float*)d_in[3];
  const float* a1s   = (const float*)d_in[4];
  const float* a1d   = (const float*)d_in[5];
  const float* b1    = (const float*)d_in[6];
  const float* W2    = (const float*)d_in[7];
  const float* a2s   = (const float*)d_in[8];
  const float* a2d   = (const float*)d_in[9];
  const float* b2    = (const float*)d_in[10];
  const float* W3    = (const float*)d_in[11];
  const float* a3s   = (const float*)d_in[12];
  const float* a3d   = (const float*)d_in[13];
  const float* b3    = (const float*)d_in[14];
  const float* Wl1   = (const float*)d_in[15];
  const float* bl1   = (const float*)d_in[16];
  const float* Wl2   = (const float*)d_in[17];
  const float* bl2   = (const float*)d_in[18];
  float* out = (float*)d_out;

  const int N = in_sizes[0] / 128;
  const int E = in_sizes[1] / 2;
  const int* src = eidx;
  const int* dst = eidx + E;
  const int NB = (N + 511) >> 9;

  // ---- workspace layout ----
  char* base = (char*)d_ws;
  size_t off = 0;
  auto alloc = [&](size_t bytes) -> void* {
    void* p = base + off;
    off += (bytes + 511) & ~(size_t)511;
    return p;
  };
  float* P        = (float*)alloc((size_t)N * 128 * 4);  // layer io, fp32
  uint*  Qb       = (uint*)alloc((size_t)N * 128 * 2);   // messages hs, packed bf16
  float* Q2       = (float*)alloc((size_t)N * 128 * 4);  // head hidden, fp32
  uint*  buckets  = (uint*)Q2;                           // alias: dead before head
  float* p_sorted = (float*)((char*)Q2 + ((size_t)24 << 20));  // alias: dead before head
  float* alpha_s  = (float*)alloc((size_t)N * 4);
  float* alpha_d  = (float*)alloc((size_t)N * 4);
  float* vs       = (float*)alloc(128 * 4);
  float* vd       = (float*)alloc(128 * 4);
  int* row_ptr    = (int*)alloc((size_t)(N + 1) * 4);
  int* bcount     = (int*)alloc(256 * 4);
  int* bbase      = (int*)alloc(256 * 4);
  int* src_sorted = (int*)alloc((size_t)E * 4);
  ushort* Wt1     = (ushort*)alloc(128 * 128 * 2);
  ushort* Wt2     = (ushort*)alloc(128 * 128 * 2);
  ushort* Wt3     = (ushort*)alloc(128 * 128 * 2);
  ushort* Wtl1    = (ushort*)alloc(128 * 128 * 2);
  ushort* Wtl2    = (ushort*)alloc(64 * 128 * 2);
  (void)ws_size;

  const int TB = 256;
  const int nwaveblk = (N + 3) / 4;
  const int ggrid = (N + 127) / 128;
  const int pagrid = (E + PA_CHUNK - 1) / PA_CHUNK;
  const int epgrid = (N + 15) / 16;

  // ---- CSR build ----
  hipMemsetAsync(bcount, 0, 256 * 4, stream);
  bucket_scatter_kernel<<<pagrid, 256, 0, stream>>>(src, dst, bcount, buckets, E, NB);
  scan_buckets_kernel<<<1, 256, 0, stream>>>(bcount, bbase, NB, row_ptr, N, E);
  bucket_sort_kernel<<<NB, 256, 0, stream>>>(buckets, bcount, bbase, row_ptr, src_sorted, N);

  // ---- weight prep (all upfront) ----
  wprep_kernel<<<8, 256, 0, stream>>>(W1s, Wt1, 128);
  wprep_kernel<<<8, 256, 0, stream>>>(W2,  Wt2, 128);
  wprep_kernel<<<8, 256, 0, stream>>>(W3,  Wt3, 128);
  wprep_kernel<<<8, 256, 0, stream>>>(Wl1, Wtl1, 128);
  wprep_kernel<<<4, 256, 0, stream>>>(Wl2, Wtl2, 64);

  // ---- layer 1: x -> P ----
  make_v2_kernel<<<64, 256, 0, stream>>>(W1s, a1s, W1d, a1d, vs, vd);
  alpha_kernel<<<nwaveblk, TB, 0, stream>>>(x, vs, vd, alpha_s, alpha_d, N);
  mfma_gemm_kernel<128, false, false, true><<<ggrid, 256, 0, stream>>>(x, Wt1, nullptr, Qb, N);
  edge_p_kernel<<<epgrid, TB, 0, stream>>>(row_ptr, src_sorted, alpha_s, alpha_d, p_sorted, N);
  gat_aggregate_kernel<<<nwaveblk, TB, 0, stream>>>(Qb, p_sorted, row_ptr, src_sorted, b1, P, N);

  // ---- layer 2: P -> P ----
  mfma_gemm_kernel<128, false, false, true><<<ggrid, 256, 0, stream>>>(P, Wt2, nullptr, Qb, N);
  alphaQ_kernel<<<nwaveblk, TB, 0, stream>>>(Qb, a2s, a2d, alpha_s, alpha_d, N);
  edge_p_kernel<<<epgrid, TB, 0, stream>>>(row_ptr, src_sorted, alpha_s, alpha_d, p_sorted, N);
  gat_aggregate_kernel<<<nwaveblk, TB, 0, stream>>>(Qb, p_sorted, row_ptr, src_sorted, b2, P, N);

  // ---- layer 3: P -> P ----
  mfma_gemm_kernel<128, false, false, true><<<ggrid, 256, 0, stream>>>(P, Wt3, nullptr, Qb, N);
  alphaQ_kernel<<<nwaveblk, TB, 0, stream>>>(Qb, a3s, a3d, alpha_s, alpha_d, N);
  edge_p_kernel<<<epgrid, TB, 0, stream>>>(row_ptr, src_sorted, alpha_s, alpha_d, p_sorted, N);
  gat_aggregate_kernel<<<nwaveblk, TB, 0, stream>>>(Qb, p_sorted, row_ptr, src_sorted, b3, P, N);

  // ---- MLP head (Q2 region free now) ----
  mfma_gemm_kernel<128, true, true, false><<<ggrid, 256, 0, stream>>>(P, Wtl1, bl1, Q2, N);
  mfma_gemm_kernel<64, false, true, false><<<ggrid, 256, 0, stream>>>(Q2, Wtl2, bl2, out, N);
}